// Round 4
// baseline (282.803 us; speedup 1.0000x reference)
//
#include <hip/hip_runtime.h>
#include <math.h>

namespace {
constexpr int K = 16, T = 8, R = 8, NB = 32;
constexpr int NX = 64, NY = 64, NZ = 32;
constexpr int NVOX = NX * NY * NZ;                 // 131072
constexpr float TWO_PI_OVER_C = (float)(6.283185307179586 / 299792458.0);
constexpr float CT_SCALE = 4.0f / 256.0f;          // folded 4 and 1/65536 split across Ht,Hr
constexpr float CR_SCALE = 1.0f / 256.0f;          // total scale = 4/65536; cancels in normalize
// B table: [tr(64)][out(2)][quad(4)][n(32)][j(8)] halves = 262144 B
constexpr int B_HALVES = 64 * 2 * 4 * 32 * 8;      // 131072
constexpr size_t WS_NEED = 256 + (size_t)B_HALVES * 2;
}

typedef _Float16 half8 __attribute__((ext_vector_type(8)));
typedef __fp16 fp16x2 __attribute__((ext_vector_type(2)));   // cvt_pkrtz native type
typedef float f32x4 __attribute__((ext_vector_type(4)));

// ---------------------------------------------------------------------------
// Prep: zero max slot; build B fragments in ws.
// B[k'][n] per (tr, out):  k'<16 -> (out0: yre, out1: yim),  k'>=16 -> (out0: -yim, out1: yre)
// ---------------------------------------------------------------------------
__global__ void prep_kernel(const float* __restrict__ yr, const float* __restrict__ yi,
                            _Float16* __restrict__ wsB, unsigned int* __restrict__ maxslot,
                            int use_ws) {
    int id = blockIdx.x * 256 + threadIdx.x;   // 16384 threads
    if (id == 0) *maxslot = 0u;
    if (!use_ws || id >= 64 * 2 * 4 * 32) return;
    int n    = id & 31;
    int quad = (id >> 5) & 3;
    int outc = (id >> 7) & 1;
    int tr   = id >> 8;
    int t = tr >> 3, r = tr & 7;
    bool second = quad >= 2;                    // k' >= 16 half (pairs with AIm)
    const float* src = (outc == 0) ? (second ? yi : yr) : (second ? yr : yi);
    float sg = (outc == 0 && second) ? -1.0f : 1.0f;
    int base = n * (K * T * R) + ((quad & 1) * 8) * (T * R) + t * R + r;
    half8 h;
#pragma unroll
    for (int j = 0; j < 8; ++j)
        h[j] = (_Float16)(sg * src[base + j * (T * R)]);
    ((half8*)wsB)[id] = h;
}

// ---------------------------------------------------------------------------
// Main: per wave, 16-voxel x 32-batch complex tile via MFMA.
// Round-1 pipeline structure (best passing config, compiler-scheduled):
// depth-2 HIP-level prefetch of B fragments (triple buffer), depth-1 LDS
// X/Z prefetch, Ht(t+1) at the midpoint of tile t. NO fences, NO inline asm
// (both regressed in rounds 2-3).
// Round-4 change: 128-thread / 2-wave / 32-voxel blocks -> Hr table 16 KB
// -> up to 10 blocks/CU (was 4 at 32.5 KB), +TLP for a latency-bound loop.
// Quad sign folded into HtIm once per t; per-wave atomicMax (no s_wmax LDS).
// ---------------------------------------------------------------------------
template <bool USE_WS>
__global__ __launch_bounds__(128, 5) void kirch_mfma(
    const float* __restrict__ freqs,
    const float* __restrict__ txp, const float* __restrict__ rxp,
    const float* __restrict__ xc, const float* __restrict__ yc, const float* __restrict__ zc,
    const _Float16* __restrict__ wsB,
    const float* __restrict__ yr, const float* __restrict__ yi,
    float* __restrict__ out, unsigned int* __restrict__ maxslot)
{
    __shared__ _Float16 sHrRe[8][2][32][8];   // [r][kh][vox][j]  8 KB
    __shared__ _Float16 sHrIm[8][2][32][8];   // 8 KB  (total 16 KB)

    const int tid  = threadIdx.x;
    const int lane = tid & 63;
    const int wave = tid >> 6;                 // 0..1
    const int nlo  = lane & 15;
    const int quad = lane >> 4;
    const int kh   = quad & 1;
    const int vb   = blockIdx.x * 32 + wave * 16;
    const int v    = vb + nlo;                 // this lane's voxel (fragment row m)
    const int bv2  = wave * 16 + nlo;          // block-local voxel index (0..31)

    const float k0 = TWO_PI_OVER_C * freqs[0];
    const float dk = TWO_PI_OVER_C * (freqs[K - 1] - freqs[0]) * (1.0f / (K - 1));

    // ---- Phase 1: cooperatively build Hr table (32 vox x 8 r x 16 k) ----
#pragma unroll
    for (int s = 0; s < 2; ++s) {
        int task = tid + (s << 7);             // 256 tasks over 128 threads
        int bv = task & 31;
        int r  = task >> 5;
        int gv = blockIdx.x * 32 + bv;
        float qx = xc[gv >> 11];
        float qy = yc[(gv >> 5) & 63];
        float qz = zc[gv & 31];
        float rxx = rxp[r * 3 + 0], rxy = rxp[r * 3 + 1], rxz = rxp[r * 3 + 2];
        float dx = qx - rxx, dy = qy - rxy, dz = qz - rxz;
        float Rr = sqrtf(dx * dx + dy * dy + dz * dz);
        float c = CR_SCALE * dz * __builtin_amdgcn_rcpf(Rr);
        float sph, cph, swp, cwp;
        __sincosf(k0 * Rr, &sph, &cph);
        __sincosf(dk * Rr, &swp, &cwp);
        float ur = cph, ui = sph;
        float ck = c * (k0 * Rr);
        const float dck = c * (dk * Rr);
        float re[16], im[16];
#pragma unroll
        for (int kk = 0; kk < 16; ++kk) {
            re[kk] = fmaf(c, ur, -(ck * ui));   // c*(ur - kR*ui)
            im[kk] = fmaf(c, ui,  (ck * ur));   // c*(ui + kR*ur)
            float nr = fmaf(ur, cwp, -(ui * swp));
            ui = fmaf(ur, swp, ui * cwp);
            ur = nr;
            ck += dck;
        }
        union { half8 v8; fp16x2 v2[4]; } h;
#pragma unroll
        for (int kk2 = 0; kk2 < 2; ++kk2) {
#pragma unroll
            for (int i = 0; i < 4; ++i)
                h.v2[i] = __builtin_amdgcn_cvt_pkrtz(re[kk2 * 8 + 2 * i], re[kk2 * 8 + 2 * i + 1]);
            *(half8*)&sHrRe[r][kk2][bv][0] = h.v8;
#pragma unroll
            for (int i = 0; i < 4; ++i)
                h.v2[i] = __builtin_amdgcn_cvt_pkrtz(im[kk2 * 8 + 2 * i], im[kk2 * 8 + 2 * i + 1]);
            *(half8*)&sHrIm[r][kk2][bv][0] = h.v8;
        }
    }
    __syncthreads();

    // ---- per-lane constants for phase 2 ----
    const float px = xc[v >> 11];
    const float py = yc[(v >> 5) & 63];
    const float pz = zc[v & 31];
    const float kstart = k0 + (kh ? 8.0f * dk : 0.0f);

    // X/Z plane selection: Re-quads compute ARe = HtRe*HrRe - HtIm*HrIm
    //                      Im-quads compute AIm = HtRe*HrIm + HtIm*HrRe
    // A = HtRe*X + HtIm'*Z with the quad sign folded into HtIm once per t.
    const _Float16* pX = (quad < 2) ? &sHrRe[0][kh][bv2][0] : &sHrIm[0][kh][bv2][0];
    const _Float16* pZ = (quad < 2) ? &sHrIm[0][kh][bv2][0] : &sHrRe[0][kh][bv2][0];
    const unsigned int sgn = (quad < 2) ? 0x80008000u : 0u;

    f32x4 accRe0 = {0,0,0,0}, accRe1 = {0,0,0,0};
    f32x4 accIm0 = {0,0,0,0}, accIm1 = {0,0,0,0};

    const char* bbase = (const char*)wsB + quad * 512 + nlo * 16;

    // Hr table r-stride in _Float16 elements: 2*32*8 = 512
    constexpr int R_STRIDE = 2 * 32 * 8;

    // Ht generator: 8-freq recurrence for tx element t, packed to fp16,
    // with the quad sign pre-applied to HtIm.
    auto computeHt = [&](int t, half8& oRe, half8& oIm) {
        const float dxt = px - txp[t * 3 + 0];
        const float dyt = py - txp[t * 3 + 1];
        const float dzt = pz - txp[t * 3 + 2];
        const float Rt = sqrtf(dxt * dxt + dyt * dyt + dzt * dzt);
        const float c = CT_SCALE * dzt * __builtin_amdgcn_rcpf(Rt);
        float sph, cph, swp, cwp;
        __sincosf(kstart * Rt, &sph, &cph);
        __sincosf(dk * Rt, &swp, &cwp);
        float ur = cph, ui = sph;
        float ck = c * (kstart * Rt);
        const float dck = c * (dk * Rt);
        float hre[8], him[8];
#pragma unroll
        for (int j = 0; j < 8; ++j) {
            hre[j] = fmaf(c, ur, -(ck * ui));
            him[j] = fmaf(c, ui,  (ck * ur));
            if (j < 7) {
                float nr = fmaf(ur, cwp, -(ui * swp));
                ui = fmaf(ur, swp, ui * cwp);
                ur = nr;
                ck += dck;
            }
        }
        union { half8 v8; fp16x2 v2[4]; unsigned int u[4]; } uRe, uIm;
#pragma unroll
        for (int i = 0; i < 4; ++i) {
            uRe.v2[i] = __builtin_amdgcn_cvt_pkrtz(hre[2 * i], hre[2 * i + 1]);
            uIm.v2[i] = __builtin_amdgcn_cvt_pkrtz(him[2 * i], him[2 * i + 1]);
        }
#pragma unroll
        for (int i = 0; i < 4; ++i) uIm.u[i] ^= sgn;   // fold quad sign into HtIm
        oRe = uRe.v8;
        oIm = uIm.v8;
    };

    // B-fragment loader. USE_WS path: 4 x 16B from the L2-resident packed
    // table. Fallback: gather+convert from fp32 y.
    auto loadB = [&](half8* dst, int tr) {
        if constexpr (USE_WS) {
            const char* bp = bbase + tr * 4096;
            dst[0] = *(const half8*)(bp);             // Re-out, ntile 0
            dst[1] = *(const half8*)(bp + 256);       // Re-out, ntile 1
            dst[2] = *(const half8*)(bp + 2048);      // Im-out, ntile 0
            dst[3] = *(const half8*)(bp + 2304);      // Im-out, ntile 1
        } else {
            const int kb = kh * 8;
            const float* sA = (quad < 2) ? yr : yi;
            const float sgA = (quad < 2) ? 1.0f : -1.0f;
            const float* sB = (quad < 2) ? yi : yr;
            auto gather = [&](const float* src, float sg, int n) {
                int base = n * (K * T * R) + kb * (T * R) + tr;
                half8 h;
#pragma unroll
                for (int j = 0; j < 8; ++j) h[j] = (_Float16)(sg * src[base + j * (T * R)]);
                return h;
            };
            dst[0] = gather(sA, sgA, nlo);
            dst[1] = gather(sA, sgA, 16 + nlo);
            dst[2] = gather(sB, 1.0f, nlo);
            dst[3] = gather(sB, 1.0f, 16 + nlo);
        }
    };

    // ---- pipeline prologue ----
    half8 htRe[2], htIm[2];
    computeHt(0, htRe[0], htIm[0]);

    half8 bb[3][4];                 // depth-2 global prefetch (triple buffer)
    half8 xzX[2], xzZ[2];           // depth-1 LDS prefetch (double buffer)
    loadB(bb[0], 0);
    loadB(bb[1], 1);
    xzX[0] = *(const half8*)(pX);
    xzZ[0] = *(const half8*)(pZ);

    // ---- main loop: 64 (t,r) pairs, fully unrolled ----
#pragma unroll
    for (int it = 0; it < 64; ++it) {
        const int t   = it >> 3;
        const int cur = it % 3;
        const int nxt = (it + 2) % 3;
        const int xc0 = it & 1;
        const int xn0 = (it + 1) & 1;

        // prefetch B fragments two iterations ahead (L2 latency cover)
        if (it + 2 < 64) loadB(bb[nxt], it + 2);
        // prefetch LDS Hr fragments one iteration ahead
        if (it + 1 < 64) {
            const int rn = (it + 1) & 7;
            xzX[xn0] = *(const half8*)(pX + rn * R_STRIDE);
            xzZ[xn0] = *(const half8*)(pZ + rn * R_STRIDE);
        }
        // precompute Ht for the next t at the midpoint of this t's r-loop
        if ((it & 7) == 4 && t < 7)
            computeHt(t + 1, htRe[(t + 1) & 1], htIm[(t + 1) & 1]);

        // ---- A fragment: packed-fp16 complex product (sign pre-folded) ----
        half8 X = xzX[xc0];
        half8 Z = xzZ[xc0];
        half8 A8 = htRe[t & 1] * X + htIm[t & 1] * Z;   // v_pk_mul/v_pk_fma

        accRe0 = __builtin_amdgcn_mfma_f32_16x16x32_f16(A8, bb[cur][0], accRe0, 0, 0, 0);
        accRe1 = __builtin_amdgcn_mfma_f32_16x16x32_f16(A8, bb[cur][1], accRe1, 0, 0, 0);
        accIm0 = __builtin_amdgcn_mfma_f32_16x16x32_f16(A8, bb[cur][2], accIm0, 0, 0, 0);
        accIm1 = __builtin_amdgcn_mfma_f32_16x16x32_f16(A8, bb[cur][3], accIm1, 0, 0, 0);
    }

    // ---- epilogue: magnitudes, store, wave max -> global atomic ----
    // C/D layout: n = ntile*16 + (lane&15), m = quad*4 + reg
    float mx = 0.0f;
#pragma unroll
    for (int reg = 0; reg < 4; ++reg) {
        const int vv = vb + quad * 4 + reg;
        float re0 = accRe0[reg], im0 = accIm0[reg];
        float m0 = sqrtf(re0 * re0 + im0 * im0);
        out[nlo * NVOX + vv] = m0;
        float re1 = accRe1[reg], im1 = accIm1[reg];
        float m1 = sqrtf(re1 * re1 + im1 * im1);
        out[(16 + nlo) * NVOX + vv] = m1;
        mx = fmaxf(mx, fmaxf(m0, m1));
    }
#pragma unroll
    for (int off = 32; off > 0; off >>= 1)
        mx = fmaxf(mx, __shfl_down(mx, off));
    if (lane == 0)
        atomicMax(maxslot, __float_as_uint(mx));   // all values >= 0
}

// ---------------------------------------------------------------------------
// Normalize: out *= 1/max
// ---------------------------------------------------------------------------
__global__ void normalize_kernel(float* __restrict__ out,
                                 const unsigned int* __restrict__ maxslot, int n4) {
    int i = blockIdx.x * blockDim.x + threadIdx.x;
    float inv = 1.0f / __uint_as_float(*maxslot);
    if (i < n4) {
        float4* o = (float4*)out;
        float4 vv = o[i];
        vv.x *= inv; vv.y *= inv; vv.z *= inv; vv.w *= inv;
        o[i] = vv;
    }
}

extern "C" void kernel_launch(void* const* d_in, const int* in_sizes, int n_in,
                              void* d_out, int out_size, void* d_ws, size_t ws_size,
                              hipStream_t stream) {
    const float* freqs = (const float*)d_in[0];
    const float* txp   = (const float*)d_in[1];
    const float* rxp   = (const float*)d_in[2];
    const float* xc    = (const float*)d_in[3];
    const float* yc    = (const float*)d_in[4];
    const float* zc    = (const float*)d_in[5];
    const float* yr    = (const float*)d_in[6];
    const float* yi    = (const float*)d_in[7];
    float* out = (float*)d_out;

    unsigned int* maxslot = (unsigned int*)d_ws;
    _Float16* wsB = (_Float16*)((char*)d_ws + 256);
    const int use_ws = (ws_size >= WS_NEED) ? 1 : 0;

    prep_kernel<<<64, 256, 0, stream>>>(yr, yi, wsB, maxslot, use_ws);

    if (use_ws)
        kirch_mfma<true><<<NVOX / 32, 128, 0, stream>>>(
            freqs, txp, rxp, xc, yc, zc, wsB, yr, yi, out, maxslot);
    else
        kirch_mfma<false><<<NVOX / 32, 128, 0, stream>>>(
            freqs, txp, rxp, xc, yc, zc, wsB, yr, yi, out, maxslot);

    int n4 = out_size / 4;
    normalize_kernel<<<(n4 + 255) / 256, 256, 0, stream>>>(out, maxslot, n4);
}

// Round 5
// 206.671 us; speedup vs baseline: 1.3684x; 1.3684x over previous
//
#include <hip/hip_runtime.h>
#include <math.h>

namespace {
constexpr int K = 16, T = 8, R = 8, NB = 32;
constexpr int NX = 64, NY = 64, NZ = 32;
constexpr int NVOX = NX * NY * NZ;                 // 131072
constexpr float TWO_PI_OVER_C = (float)(6.283185307179586 / 299792458.0);
constexpr float CT_SCALE = 4.0f / 256.0f;          // folded 4 and 1/65536 split across Ht,Hr
constexpr float CR_SCALE = 1.0f / 256.0f;          // total scale = 4/65536; cancels in normalize
// B table: [tr(64)][out(2)][quad(4)][n(32)][j(8)] halves = 262144 B
constexpr int B_HALVES = 64 * 2 * 4 * 32 * 8;      // 131072
constexpr size_t WS_NEED = 256 + (size_t)B_HALVES * 2;
}

typedef _Float16 half8 __attribute__((ext_vector_type(8)));
typedef __fp16 fp16x2 __attribute__((ext_vector_type(2)));   // cvt_pkrtz native type
typedef float f32x4 __attribute__((ext_vector_type(4)));

// ---------------------------------------------------------------------------
// Prep: zero max slot; build B fragments in ws.
// B[k'][n] per (tr, out):  k'<16 -> (out0: yre, out1: yim),  k'>=16 -> (out0: -yim, out1: yre)
// ---------------------------------------------------------------------------
__global__ void prep_kernel(const float* __restrict__ yr, const float* __restrict__ yi,
                            _Float16* __restrict__ wsB, unsigned int* __restrict__ maxslot,
                            int use_ws) {
    int id = blockIdx.x * 256 + threadIdx.x;   // 16384 threads
    if (id == 0) *maxslot = 0u;
    if (!use_ws || id >= 64 * 2 * 4 * 32) return;
    int n    = id & 31;
    int quad = (id >> 5) & 3;
    int outc = (id >> 7) & 1;
    int tr   = id >> 8;
    int t = tr >> 3, r = tr & 7;
    bool second = quad >= 2;                    // k' >= 16 half (pairs with AIm)
    const float* src = (outc == 0) ? (second ? yi : yr) : (second ? yr : yi);
    float sg = (outc == 0 && second) ? -1.0f : 1.0f;
    int base = n * (K * T * R) + ((quad & 1) * 8) * (T * R) + t * R + r;
    half8 h;
#pragma unroll
    for (int j = 0; j < 8; ++j)
        h[j] = (_Float16)(sg * src[base + j * (T * R)]);
    ((half8*)wsB)[id] = h;
}

// ---------------------------------------------------------------------------
// Main: per wave, 16-voxel x 32-batch complex tile via MFMA.
// Round-1 structure verbatim (best passing: 108 us main kernel): 256-thread
// / 64-voxel blocks, compiler-scheduled depth-2 B prefetch (triple buffer),
// depth-1 LDS X/Z prefetch, Ht(t+1) at the midpoint of tile t. NO fences,
// NO inline-asm memory ops (rounds 2-4 all regressed).
// Round-5 isolated change: LDS exactly 32768 B (s_wmax dropped; per-wave
// atomicMax) -> LDS residency cap moves 4 -> 5 blocks/CU (5*32768 = 160 KiB
// exactly) = 20 waves/CU, +25% TLP for a latency-bound loop.
// Also keeps the correctness-verified quad-sign fold into HtIm (1x per t,
// removes the per-iteration Z-XOR).
// ---------------------------------------------------------------------------
template <bool USE_WS>
__global__ __launch_bounds__(256, 4) void kirch_mfma(
    const float* __restrict__ freqs,
    const float* __restrict__ txp, const float* __restrict__ rxp,
    const float* __restrict__ xc, const float* __restrict__ yc, const float* __restrict__ zc,
    const _Float16* __restrict__ wsB,
    const float* __restrict__ yr, const float* __restrict__ yi,
    float* __restrict__ out, unsigned int* __restrict__ maxslot)
{
    __shared__ _Float16 sHrRe[8][2][64][8];   // [r][kh][vox][j]  16 KB
    __shared__ _Float16 sHrIm[8][2][64][8];   // 16 KB  (total exactly 32 KB)

    const int tid  = threadIdx.x;
    const int lane = tid & 63;
    const int wave = tid >> 6;
    const int nlo  = lane & 15;
    const int quad = lane >> 4;
    const int kh   = quad & 1;
    const int vb   = blockIdx.x * 64 + wave * 16;
    const int v    = vb + nlo;                 // this lane's voxel (fragment row m)
    const int bv2  = wave * 16 + nlo;          // block-local voxel index

    const float k0 = TWO_PI_OVER_C * freqs[0];
    const float dk = TWO_PI_OVER_C * (freqs[K - 1] - freqs[0]) * (1.0f / (K - 1));

    // ---- Phase 1: cooperatively build Hr table (64 vox x 8 r x 16 k) ----
#pragma unroll
    for (int s = 0; s < 2; ++s) {
        int task = tid + (s << 8);             // 512 tasks
        int bv = task & 63;
        int r  = task >> 6;
        int gv = blockIdx.x * 64 + bv;
        float qx = xc[gv >> 11];
        float qy = yc[(gv >> 5) & 63];
        float qz = zc[gv & 31];
        float rxx = rxp[r * 3 + 0], rxy = rxp[r * 3 + 1], rxz = rxp[r * 3 + 2];
        float dx = qx - rxx, dy = qy - rxy, dz = qz - rxz;
        float Rr = sqrtf(dx * dx + dy * dy + dz * dz);
        float c = CR_SCALE * dz * __builtin_amdgcn_rcpf(Rr);
        float sph, cph, swp, cwp;
        __sincosf(k0 * Rr, &sph, &cph);
        __sincosf(dk * Rr, &swp, &cwp);
        float ur = cph, ui = sph;
        float ck = c * (k0 * Rr);
        const float dck = c * (dk * Rr);
        float re[16], im[16];
#pragma unroll
        for (int kk = 0; kk < 16; ++kk) {
            re[kk] = fmaf(c, ur, -(ck * ui));   // c*(ur - kR*ui)
            im[kk] = fmaf(c, ui,  (ck * ur));   // c*(ui + kR*ur)
            float nr = fmaf(ur, cwp, -(ui * swp));
            ui = fmaf(ur, swp, ui * cwp);
            ur = nr;
            ck += dck;
        }
        union { half8 v8; fp16x2 v2[4]; } h;
#pragma unroll
        for (int kk2 = 0; kk2 < 2; ++kk2) {
#pragma unroll
            for (int i = 0; i < 4; ++i)
                h.v2[i] = __builtin_amdgcn_cvt_pkrtz(re[kk2 * 8 + 2 * i], re[kk2 * 8 + 2 * i + 1]);
            *(half8*)&sHrRe[r][kk2][bv][0] = h.v8;
#pragma unroll
            for (int i = 0; i < 4; ++i)
                h.v2[i] = __builtin_amdgcn_cvt_pkrtz(im[kk2 * 8 + 2 * i], im[kk2 * 8 + 2 * i + 1]);
            *(half8*)&sHrIm[r][kk2][bv][0] = h.v8;
        }
    }
    __syncthreads();

    // ---- per-lane constants for phase 2 ----
    const float px = xc[v >> 11];
    const float py = yc[(v >> 5) & 63];
    const float pz = zc[v & 31];
    const float kstart = k0 + (kh ? 8.0f * dk : 0.0f);

    // X/Z plane selection: Re-quads compute ARe = HtRe*HrRe - HtIm*HrIm
    //                      Im-quads compute AIm = HtRe*HrIm + HtIm*HrRe
    // A = HtRe*X + HtIm'*Z with the quad sign folded into HtIm once per t.
    const _Float16* pX = (quad < 2) ? &sHrRe[0][kh][bv2][0] : &sHrIm[0][kh][bv2][0];
    const _Float16* pZ = (quad < 2) ? &sHrIm[0][kh][bv2][0] : &sHrRe[0][kh][bv2][0];
    const unsigned int sgn = (quad < 2) ? 0x80008000u : 0u;

    f32x4 accRe0 = {0,0,0,0}, accRe1 = {0,0,0,0};
    f32x4 accIm0 = {0,0,0,0}, accIm1 = {0,0,0,0};

    const char* bbase = (const char*)wsB + quad * 512 + nlo * 16;

    // Ht generator: 8-freq recurrence for tx element t, packed to fp16,
    // with the quad sign pre-applied to HtIm.
    auto computeHt = [&](int t, half8& oRe, half8& oIm) {
        const float dxt = px - txp[t * 3 + 0];
        const float dyt = py - txp[t * 3 + 1];
        const float dzt = pz - txp[t * 3 + 2];
        const float Rt = sqrtf(dxt * dxt + dyt * dyt + dzt * dzt);
        const float c = CT_SCALE * dzt * __builtin_amdgcn_rcpf(Rt);
        float sph, cph, swp, cwp;
        __sincosf(kstart * Rt, &sph, &cph);
        __sincosf(dk * Rt, &swp, &cwp);
        float ur = cph, ui = sph;
        float ck = c * (kstart * Rt);
        const float dck = c * (dk * Rt);
        float hre[8], him[8];
#pragma unroll
        for (int j = 0; j < 8; ++j) {
            hre[j] = fmaf(c, ur, -(ck * ui));
            him[j] = fmaf(c, ui,  (ck * ur));
            if (j < 7) {
                float nr = fmaf(ur, cwp, -(ui * swp));
                ui = fmaf(ur, swp, ui * cwp);
                ur = nr;
                ck += dck;
            }
        }
        union { half8 v8; fp16x2 v2[4]; unsigned int u[4]; } uRe, uIm;
#pragma unroll
        for (int i = 0; i < 4; ++i) {
            uRe.v2[i] = __builtin_amdgcn_cvt_pkrtz(hre[2 * i], hre[2 * i + 1]);
            uIm.v2[i] = __builtin_amdgcn_cvt_pkrtz(him[2 * i], him[2 * i + 1]);
        }
#pragma unroll
        for (int i = 0; i < 4; ++i) uIm.u[i] ^= sgn;   // fold quad sign into HtIm
        oRe = uRe.v8;
        oIm = uIm.v8;
    };

    // B-fragment loader. USE_WS path: 4 x 16B from the L2-resident packed
    // table. Fallback: gather+convert from fp32 y.
    auto loadB = [&](half8* dst, int tr) {
        if constexpr (USE_WS) {
            const char* bp = bbase + tr * 4096;
            dst[0] = *(const half8*)(bp);             // Re-out, ntile 0
            dst[1] = *(const half8*)(bp + 256);       // Re-out, ntile 1
            dst[2] = *(const half8*)(bp + 2048);      // Im-out, ntile 0
            dst[3] = *(const half8*)(bp + 2304);      // Im-out, ntile 1
        } else {
            const int kb = kh * 8;
            const float* sA = (quad < 2) ? yr : yi;
            const float sgA = (quad < 2) ? 1.0f : -1.0f;
            const float* sB = (quad < 2) ? yi : yr;
            auto gather = [&](const float* src, float sg, int n) {
                int base = n * (K * T * R) + kb * (T * R) + tr;
                half8 h;
#pragma unroll
                for (int j = 0; j < 8; ++j) h[j] = (_Float16)(sg * src[base + j * (T * R)]);
                return h;
            };
            dst[0] = gather(sA, sgA, nlo);
            dst[1] = gather(sA, sgA, 16 + nlo);
            dst[2] = gather(sB, 1.0f, nlo);
            dst[3] = gather(sB, 1.0f, 16 + nlo);
        }
    };

    // ---- pipeline prologue ----
    half8 htRe[2], htIm[2];
    computeHt(0, htRe[0], htIm[0]);

    half8 bb[3][4];                 // depth-2 global prefetch (triple buffer)
    half8 xzX[2], xzZ[2];           // depth-1 LDS prefetch (double buffer)
    loadB(bb[0], 0);
    loadB(bb[1], 1);
    xzX[0] = *(const half8*)(pX);
    xzZ[0] = *(const half8*)(pZ);

    // ---- main loop: 64 (t,r) pairs, fully unrolled ----
#pragma unroll
    for (int it = 0; it < 64; ++it) {
        const int t   = it >> 3;
        const int cur = it % 3;
        const int nxt = (it + 2) % 3;
        const int xc0 = it & 1;
        const int xn0 = (it + 1) & 1;

        // prefetch B fragments two iterations ahead (L2 latency cover)
        if (it + 2 < 64) loadB(bb[nxt], it + 2);
        // prefetch LDS Hr fragments one iteration ahead
        if (it + 1 < 64) {
            const int rn = (it + 1) & 7;
            xzX[xn0] = *(const half8*)(pX + rn * 1024);
            xzZ[xn0] = *(const half8*)(pZ + rn * 1024);
        }
        // precompute Ht for the next t at the midpoint of this t's r-loop
        if ((it & 7) == 4 && t < 7)
            computeHt(t + 1, htRe[(t + 1) & 1], htIm[(t + 1) & 1]);

        // ---- A fragment: packed-fp16 complex product (sign pre-folded) ----
        half8 X = xzX[xc0];
        half8 Z = xzZ[xc0];
        half8 A8 = htRe[t & 1] * X + htIm[t & 1] * Z;   // v_pk_mul/v_pk_fma

        accRe0 = __builtin_amdgcn_mfma_f32_16x16x32_f16(A8, bb[cur][0], accRe0, 0, 0, 0);
        accRe1 = __builtin_amdgcn_mfma_f32_16x16x32_f16(A8, bb[cur][1], accRe1, 0, 0, 0);
        accIm0 = __builtin_amdgcn_mfma_f32_16x16x32_f16(A8, bb[cur][2], accIm0, 0, 0, 0);
        accIm1 = __builtin_amdgcn_mfma_f32_16x16x32_f16(A8, bb[cur][3], accIm1, 0, 0, 0);
    }

    // ---- epilogue: magnitudes, store, wave max -> global atomic ----
    // C/D layout: n = ntile*16 + (lane&15), m = quad*4 + reg
    float mx = 0.0f;
#pragma unroll
    for (int reg = 0; reg < 4; ++reg) {
        const int vv = vb + quad * 4 + reg;
        float re0 = accRe0[reg], im0 = accIm0[reg];
        float m0 = sqrtf(re0 * re0 + im0 * im0);
        out[nlo * NVOX + vv] = m0;
        float re1 = accRe1[reg], im1 = accIm1[reg];
        float m1 = sqrtf(re1 * re1 + im1 * im1);
        out[(16 + nlo) * NVOX + vv] = m1;
        mx = fmaxf(mx, fmaxf(m0, m1));
    }
#pragma unroll
    for (int off = 32; off > 0; off >>= 1)
        mx = fmaxf(mx, __shfl_down(mx, off));
    if (lane == 0)
        atomicMax(maxslot, __float_as_uint(mx));   // all values >= 0
}

// ---------------------------------------------------------------------------
// Normalize: out *= 1/max
// ---------------------------------------------------------------------------
__global__ void normalize_kernel(float* __restrict__ out,
                                 const unsigned int* __restrict__ maxslot, int n4) {
    int i = blockIdx.x * blockDim.x + threadIdx.x;
    float inv = 1.0f / __uint_as_float(*maxslot);
    if (i < n4) {
        float4* o = (float4*)out;
        float4 vv = o[i];
        vv.x *= inv; vv.y *= inv; vv.z *= inv; vv.w *= inv;
        o[i] = vv;
    }
}

extern "C" void kernel_launch(void* const* d_in, const int* in_sizes, int n_in,
                              void* d_out, int out_size, void* d_ws, size_t ws_size,
                              hipStream_t stream) {
    const float* freqs = (const float*)d_in[0];
    const float* txp   = (const float*)d_in[1];
    const float* rxp   = (const float*)d_in[2];
    const float* xc    = (const float*)d_in[3];
    const float* yc    = (const float*)d_in[4];
    const float* zc    = (const float*)d_in[5];
    const float* yr    = (const float*)d_in[6];
    const float* yi    = (const float*)d_in[7];
    float* out = (float*)d_out;

    unsigned int* maxslot = (unsigned int*)d_ws;
    _Float16* wsB = (_Float16*)((char*)d_ws + 256);
    const int use_ws = (ws_size >= WS_NEED) ? 1 : 0;

    prep_kernel<<<64, 256, 0, stream>>>(yr, yi, wsB, maxslot, use_ws);

    if (use_ws)
        kirch_mfma<true><<<NVOX / 64, 256, 0, stream>>>(
            freqs, txp, rxp, xc, yc, zc, wsB, yr, yi, out, maxslot);
    else
        kirch_mfma<false><<<NVOX / 64, 256, 0, stream>>>(
            freqs, txp, rxp, xc, yc, zc, wsB, yr, yi, out, maxslot);

    int n4 = out_size / 4;
    normalize_kernel<<<(n4 + 255) / 256, 256, 0, stream>>>(out, maxslot, n4);
}

// Round 6
// 130.040 us; speedup vs baseline: 2.1747x; 1.5893x over previous
//
#include <hip/hip_runtime.h>
#include <math.h>

namespace {
constexpr int K = 16, T = 8, R = 8, NB = 32;
constexpr int NX = 64, NY = 64, NZ = 32;
constexpr int NVOX = NX * NY * NZ;                 // 131072
constexpr float TWO_PI_OVER_C = (float)(6.283185307179586 / 299792458.0);
constexpr float CT_SCALE = 4.0f / 256.0f;          // folded 4 and 1/65536 split across Ht,Hr
constexpr float CR_SCALE = 1.0f / 256.0f;          // total scale = 4/65536; cancels in normalize
// B table: [tr(64)][frag(3: yRe,yIm,-yIm)][kc(2)][n(32)][j(8)] halves = 196608 B
constexpr int B_HALVES = 64 * 3 * 2 * 32 * 8;      // 98304
constexpr size_t WS_NEED = 256 + (size_t)B_HALVES * 2;
}

typedef _Float16 half8 __attribute__((ext_vector_type(8)));
typedef __fp16 fp16x2 __attribute__((ext_vector_type(2)));   // cvt_pkrtz native type
typedef float f32x16 __attribute__((ext_vector_type(16)));

// ---------------------------------------------------------------------------
// Prep: zero max slot; build B fragments in ws for the 32x32x16 layout.
// B[k][n] per (tr, frag): frag 0 = yRe, 1 = yIm, 2 = -yIm; k = kc*8 + j.
// halves index = (((tr*3 + f)*2 + kc)*32 + n)*8 + j  == id*8 + j.
// ---------------------------------------------------------------------------
__global__ void prep_kernel(const float* __restrict__ yr, const float* __restrict__ yi,
                            _Float16* __restrict__ wsB, unsigned int* __restrict__ maxslot,
                            int use_ws) {
    int id = blockIdx.x * 256 + threadIdx.x;   // 12288 tasks
    if (id == 0) *maxslot = 0u;
    if (!use_ws || id >= 64 * 3 * 2 * 32) return;
    int n    = id & 31;
    int rest = id >> 5;            // (tr*3 + f)*2 + kc
    int kc   = rest & 1;
    int ftr  = rest >> 1;          // tr*3 + f
    int f    = ftr % 3;
    int tr   = ftr / 3;
    int t = tr >> 3, r = tr & 7;
    const float* src = (f == 0) ? yr : yi;
    float sg = (f == 2) ? -1.0f : 1.0f;
    int base = n * (K * T * R) + (kc * 8) * (T * R) + t * R + r;
    half8 h;
#pragma unroll
    for (int j = 0; j < 8; ++j)
        h[j] = (_Float16)(sg * src[base + j * (T * R)]);
    ((half8*)wsB)[id] = h;
}

// ---------------------------------------------------------------------------
// Main: per wave, 32-voxel x 32-batch complex tile via mfma_f32_32x32x16_f16.
// A layout (same mapping rule the passing 16x16x32 kernel validates):
//   row = lane&31 (voxel), k = (lane>>5)*8 + j (freq). One voxel per lane ->
//   Hr is lane-local and lives in 64 VGPRs (8 r x half8 Re/Im); NO LDS table,
//   no barriers, no ds_reads in the hot loop.
// Per (t,r): ARe/AIm packed complex products (Ht x cached Hr), 3 B fragments
// (yRe, yIm, -yIm; yRe reused by both outputs), 4 MFMAs:
//   accRe += ARe*yRe + AIm*(-yIm);  accIm += ARe*yIm + AIm*yRe.
// Ht(t+1) computed at the midpoint of tile t (proven round-1 pattern).
// C/D layout (HW-verified): col = lane&31 = n, row = (reg&3)+8*(reg>>2)+4*kc.
// ---------------------------------------------------------------------------
template <bool USE_WS>
__global__ __launch_bounds__(256, 3) void kirch_mfma(
    const float* __restrict__ freqs,
    const float* __restrict__ txp, const float* __restrict__ rxp,
    const float* __restrict__ xc, const float* __restrict__ yc, const float* __restrict__ zc,
    const _Float16* __restrict__ wsB,
    const float* __restrict__ yr, const float* __restrict__ yi,
    float* __restrict__ out, unsigned int* __restrict__ maxslot)
{
    __shared__ float s_wmax[4];

    const int tid  = threadIdx.x;
    const int lane = tid & 63;
    const int wave = tid >> 6;
    const int ml   = lane & 31;                // voxel row (A) / batch col (B,C)
    const int kc   = lane >> 5;                // freq-half select
    const int vb   = blockIdx.x * 128 + wave * 32;
    const int v    = vb + ml;                  // this lane's voxel

    const float k0 = TWO_PI_OVER_C * freqs[0];
    const float dk = TWO_PI_OVER_C * (freqs[K - 1] - freqs[0]) * (1.0f / (K - 1));
    const float kstart = k0 + (float)(kc * 8) * dk;

    const float px = xc[v >> 11];
    const float py = yc[(v >> 5) & 63];
    const float pz = zc[v & 31];

    // H generator: 8-freq recurrence starting at kstart for element at (sx,sy,sz).
    auto computeH = [&](float sx, float sy, float sz, float scale, half8& oRe, half8& oIm) {
        const float dx = px - sx, dy = py - sy, dz = pz - sz;
        const float Rr = sqrtf(dx * dx + dy * dy + dz * dz);
        const float c = scale * dz * __builtin_amdgcn_rcpf(Rr);
        float sph, cph, swp, cwp;
        __sincosf(kstart * Rr, &sph, &cph);
        __sincosf(dk * Rr, &swp, &cwp);
        float ur = cph, ui = sph;
        float ck = c * (kstart * Rr);
        const float dck = c * (dk * Rr);
        float hre[8], him[8];
#pragma unroll
        for (int j = 0; j < 8; ++j) {
            hre[j] = fmaf(c, ur, -(ck * ui));   // c*(ur - kR*ui)
            him[j] = fmaf(c, ui,  (ck * ur));   // c*(ui + kR*ur)
            if (j < 7) {
                float nr = fmaf(ur, cwp, -(ui * swp));
                ui = fmaf(ur, swp, ui * cwp);
                ur = nr;
                ck += dck;
            }
        }
        union { half8 v8; fp16x2 v2[4]; } uRe, uIm;
#pragma unroll
        for (int i = 0; i < 4; ++i) {
            uRe.v2[i] = __builtin_amdgcn_cvt_pkrtz(hre[2 * i], hre[2 * i + 1]);
            uIm.v2[i] = __builtin_amdgcn_cvt_pkrtz(him[2 * i], him[2 * i + 1]);
        }
        oRe = uRe.v8;
        oIm = uIm.v8;
    };

    // ---- prologue: Hr for all 8 rx elements, register-resident (64 VGPRs) ----
    half8 hrRe[8], hrIm[8];
#pragma unroll
    for (int r = 0; r < 8; ++r)
        computeH(rxp[r * 3 + 0], rxp[r * 3 + 1], rxp[r * 3 + 2], CR_SCALE, hrRe[r], hrIm[r]);

    f32x16 accRe = {0,0,0,0,0,0,0,0,0,0,0,0,0,0,0,0};
    f32x16 accIm = {0,0,0,0,0,0,0,0,0,0,0,0,0,0,0,0};

    const char* bbase = (const char*)wsB + kc * 512 + ml * 16;

    // B fragments, double-buffered. frag byte offsets within a tr-slot (3072 B):
    // yRe @ +0, yIm @ +1024, -yIm @ +2048.
    half8 bRe[2], bIm[2], bNi[2];
    auto loadB = [&](int buf, int tr) {
        if constexpr (USE_WS) {
            const char* bp = bbase + tr * 3072;
            bRe[buf] = *(const half8*)(bp);
            bIm[buf] = *(const half8*)(bp + 1024);
            bNi[buf] = *(const half8*)(bp + 2048);
        } else {
            int t = tr >> 3, r = tr & 7;
            int base = ml * (K * T * R) + (kc * 8) * (T * R) + t * R + r;
            half8 a, b, c2;
#pragma unroll
            for (int j = 0; j < 8; ++j) {
                float vre = yr[base + j * (T * R)];
                float vim = yi[base + j * (T * R)];
                a[j]  = (_Float16)vre;
                b[j]  = (_Float16)vim;
                c2[j] = (_Float16)(-vim);
            }
            bRe[buf] = a; bIm[buf] = b; bNi[buf] = c2;
        }
    };

    // ---- pipeline prologue ----
    half8 htRe[2], htIm[2];
    computeH(txp[0], txp[1], txp[2], CT_SCALE, htRe[0], htIm[0]);
    loadB(0, 0);

    // ---- main loop: 64 (t,r) pairs, fully unrolled, static indices ----
#pragma unroll
    for (int it = 0; it < 64; ++it) {
        const int t   = it >> 3;
        const int r   = it & 7;
        const int cur = it & 1;
        const int nxt = cur ^ 1;

        // prefetch next iteration's B fragments (L2-resident)
        if (it + 1 < 64) loadB(nxt, it + 1);
        // next t's Ht at the midpoint of this t's r-sweep (hides serial chain)
        if (r == 4 && t < 7)
            computeH(txp[(t + 1) * 3 + 0], txp[(t + 1) * 3 + 1], txp[(t + 1) * 3 + 2],
                     CT_SCALE, htRe[(t + 1) & 1], htIm[(t + 1) & 1]);

        // ---- A fragments: packed-fp16 complex products ----
        half8 hRe = htRe[t & 1], hIm = htIm[t & 1];
        half8 ARe = hRe * hrRe[r] - hIm * hrIm[r];
        half8 AIm = hRe * hrIm[r] + hIm * hrRe[r];

        accRe = __builtin_amdgcn_mfma_f32_32x32x16_f16(ARe, bRe[cur], accRe, 0, 0, 0);
        accIm = __builtin_amdgcn_mfma_f32_32x32x16_f16(ARe, bIm[cur], accIm, 0, 0, 0);
        accRe = __builtin_amdgcn_mfma_f32_32x32x16_f16(AIm, bNi[cur], accRe, 0, 0, 0);
        accIm = __builtin_amdgcn_mfma_f32_32x32x16_f16(AIm, bRe[cur], accIm, 0, 0, 0);
    }

    // ---- epilogue: magnitudes, float4 stores, block max ----
    // C/D: n = ml, vox = vb + (reg&3) + 8*(reg>>2) + 4*kc  (reg&3 -> contiguous)
    float mx = 0.0f;
#pragma unroll
    for (int g = 0; g < 4; ++g) {
        float om[4];
#pragma unroll
        for (int e = 0; e < 4; ++e) {
            float re = accRe[4 * g + e], im = accIm[4 * g + e];
            float m = sqrtf(re * re + im * im);
            om[e] = m;
            mx = fmaxf(mx, m);
        }
        *(float4*)&out[ml * NVOX + vb + 8 * g + 4 * kc] = *(float4*)om;
    }
#pragma unroll
    for (int off = 32; off > 0; off >>= 1)
        mx = fmaxf(mx, __shfl_down(mx, off));
    if (lane == 0) s_wmax[wave] = mx;
    __syncthreads();
    if (tid == 0) {
        float bm = fmaxf(fmaxf(s_wmax[0], s_wmax[1]), fmaxf(s_wmax[2], s_wmax[3]));
        atomicMax(maxslot, __float_as_uint(bm));
    }
}

// ---------------------------------------------------------------------------
// Normalize: out *= 1/max
// ---------------------------------------------------------------------------
__global__ void normalize_kernel(float* __restrict__ out,
                                 const unsigned int* __restrict__ maxslot, int n4) {
    int i = blockIdx.x * blockDim.x + threadIdx.x;
    float inv = 1.0f / __uint_as_float(*maxslot);
    if (i < n4) {
        float4* o = (float4*)out;
        float4 vv = o[i];
        vv.x *= inv; vv.y *= inv; vv.z *= inv; vv.w *= inv;
        o[i] = vv;
    }
}

extern "C" void kernel_launch(void* const* d_in, const int* in_sizes, int n_in,
                              void* d_out, int out_size, void* d_ws, size_t ws_size,
                              hipStream_t stream) {
    const float* freqs = (const float*)d_in[0];
    const float* txp   = (const float*)d_in[1];
    const float* rxp   = (const float*)d_in[2];
    const float* xc    = (const float*)d_in[3];
    const float* yc    = (const float*)d_in[4];
    const float* zc    = (const float*)d_in[5];
    const float* yr    = (const float*)d_in[6];
    const float* yi    = (const float*)d_in[7];
    float* out = (float*)d_out;

    unsigned int* maxslot = (unsigned int*)d_ws;
    _Float16* wsB = (_Float16*)((char*)d_ws + 256);
    const int use_ws = (ws_size >= WS_NEED) ? 1 : 0;

    prep_kernel<<<48, 256, 0, stream>>>(yr, yi, wsB, maxslot, use_ws);

    if (use_ws)
        kirch_mfma<true><<<NVOX / 128, 256, 0, stream>>>(
            freqs, txp, rxp, xc, yc, zc, wsB, yr, yi, out, maxslot);
    else
        kirch_mfma<false><<<NVOX / 128, 256, 0, stream>>>(
            freqs, txp, rxp, xc, yc, zc, wsB, yr, yi, out, maxslot);

    int n4 = out_size / 4;
    normalize_kernel<<<(n4 + 255) / 256, 256, 0, stream>>>(out, maxslot, n4);
}